// Round 5
// baseline (131.700 us; speedup 1.0000x reference)
//
#include <hip/hip_runtime.h>
#include <math.h>

// ---------------------------------------------------------------------------
// N=4, T=2048, D_MODEL=512, NHEAD=8, HEAD_DIM=64, window -127..+128.
// Pipeline: cvt_all -> bf16 ; qkv = x@Wqkv^T + fused RoPE + q-scale (MFMA,
// 2-phase counted-vmcnt pipeline) ; flash attn (MFMA, swapped-QK^T in-register
// softmax) ; out GEMM.
// R18: GEMM k-loop rebuilt as 2-phase counted-vmcnt pipeline (T3/T4 minimum
// form): BK 64->32 with physically-split half-buffers As[2][128][32] /
// Bs[2][64][32] (same 24KB LDS, same (256,5) -> 5 blocks/CU preserved).
// Per iter: stage(t+1) -> s_waitcnt vmcnt(3) (t landed, t+1 in flight) ->
// raw s_barrier -> 6 ds_read + 8 MFMA -> raw s_barrier. No __syncthreads in
// the loop => no compiler-injected vmcnt(0) full drain. Swizzle re-derived
// for 32-wide halves (XOR (r&3)*8, ~2-way bank alias = free); staging swizzle
// on the GLOBAL source side only (gload_lds dest must be wave-linear).
// R17: swapped QK^T in-register softmax (kept, -2.2us).
// R16 lesson: attn reg-prefetch bundle regressed (occupancy) — reverted.
// R15 lesson: occupancy > tile density at K=512 (128x128 GEMM tile reverted).
// R14: V written PRE-TRANSPOSED to vT[n][h][d][t] by the QKV GEMM (kept).
// ---------------------------------------------------------------------------

typedef __attribute__((ext_vector_type(8))) __bf16 bf16x8;
typedef __attribute__((ext_vector_type(4))) float f32x4;

__device__ __forceinline__ unsigned short f2bf(float f) {
    unsigned int u = __float_as_uint(f);
    u += 0x7fffu + ((u >> 16) & 1u);
    return (unsigned short)(u >> 16);
}
__device__ __forceinline__ unsigned int packbf2(float a, float b) {
    unsigned int ua = __float_as_uint(a); ua += 0x7fffu + ((ua >> 16) & 1u);
    unsigned int ub = __float_as_uint(b); ub += 0x7fffu + ((ub >> 16) & 1u);
    return (ua >> 16) | (ub & 0xffff0000u);
}
__device__ __forceinline__ bf16x8 as_bf16x8(uint4 u) {
    union { uint4 u4; bf16x8 v; } c; c.u4 = u; return c.v;
}
__device__ __forceinline__ bf16x8 ld_frag(const unsigned short* p) {
    return as_bf16x8(*(const uint4*)p);
}

__device__ __forceinline__ void async16(void* lds, const void* g) {
    __builtin_amdgcn_global_load_lds(
        (const __attribute__((address_space(1))) void*)g,
        (__attribute__((address_space(3))) void*)lds,
        16, 0, 0);
}

// One kernel converts all three fp32 inputs to bf16 (4 elems/thread).
__global__ __launch_bounds__(256) void cvt_all(
    const float* __restrict__ x, const float* __restrict__ w1,
    const float* __restrict__ w2,
    unsigned short* __restrict__ xb, unsigned short* __restrict__ w1b,
    unsigned short* __restrict__ w2b)
{
    const int n_x  = 8192 * 512 / 4;
    const int n_w1 = 1536 * 512 / 4;
    const int n_w2 = 512 * 512 / 4;
    int i = blockIdx.x * 256 + threadIdx.x;
    const float* in; unsigned short* out; int j;
    if (i < n_x)                    { in = x;  out = xb;  j = i; }
    else if (i < n_x + n_w1)        { in = w1; out = w1b; j = i - n_x; }
    else if (i < n_x + n_w1 + n_w2) { in = w2; out = w2b; j = i - n_x - n_w1; }
    else return;
    float4 v = *(const float4*)(in + 4 * (size_t)j);
    uint2 o;
    o.x = packbf2(v.x, v.y);
    o.y = packbf2(v.z, v.w);
    *(uint2*)(out + 4 * (size_t)j) = o;
}

// C[M,O] = A[M,K](bf16) * B[O,K](bf16)^T (+bias). Output fp32 or bf16.
// BM=128, BN=64, BK=32 x 2-phase. Block=256 (4 waves); wave w computes rows
// [w*32,+32) x all 64 cols (mt=2, nt=4; acc 32 AGPR).
// __launch_bounds__(256,5): 5 blocks/CU (R13/R15 lesson: occupancy wins).
// 2-phase k-loop: stage(t+1) issued before compute(t); vmcnt(3) keeps t+1's
// loads in flight across barriers (never vmcnt(0) in-loop). Raw s_barrier
// (NOT __syncthreads — would re-inject the full drain).
// LDS halves [2][*][32]; logical k stored at chunk (k^((r&3)*8)) via
// global-side swizzle (gload_lds dest stays wave-linear); reads use the
// same XOR => conflict ~2-way (free).
// do_rope: qkv layout (O=1536); RoPE cols<1024 (partner col^32 == acc nt^2,
// same thread), fold 1/8 into q cols<512. V cols (>=1024) are written
// transposed to vT[n][h][dim][t] as packed 8B stores (attn consumes V^T).
__global__ __launch_bounds__(256, 5) void gemm_bt_mfma(
    const unsigned short* __restrict__ A, const unsigned short* __restrict__ B,
    const float* __restrict__ bias, void* __restrict__ Cout,
    int M, int O, int K, int write_bf16, int do_rope,
    unsigned short* __restrict__ vT)
{
    __shared__ __align__(16) unsigned short As[2][128 * 32];   // 16 KB
    __shared__ __align__(16) unsigned short Bs[2][64 * 32];    // 8 KB

    const int tid  = threadIdx.x;
    const int wave = tid >> 6;
    const int lane = tid & 63;
    const int l15  = lane & 15;
    const int lg   = lane >> 4;
    const int row0 = blockIdx.x * 128;
    const int col0 = blockIdx.y * 64;
    const int wr   = wave * 32;

    f32x4 acc[2][4] = {};

    // staging: thread -> (row sr2 per 64-block, chunk tid&3); global k gets
    // the XOR swizzle, LDS dest is linear (gload_lds constraint).
    const int sr2 = tid >> 2;                       // 0..63
    const int skg = ((tid & 3) * 8) ^ ((sr2 & 3) * 8);  // swizzled k within 32
    const int fx3 = (l15 & 3) * 8;

    const int NT = K >> 5;   // 32-wide k-tiles

    // prologue: stage tile 0 into half 0, drain, sync
    {
        #pragma unroll
        for (int s = 0; s < 2; ++s)
            async16(&As[0][(size_t)(s * 256 + tid) * 8],
                    A + (size_t)(row0 + s * 64 + sr2) * K + skg);
        async16(&Bs[0][(size_t)tid * 8],
                B + (size_t)(col0 + sr2) * K + skg);
    }
    asm volatile("s_waitcnt vmcnt(0)" ::: "memory");
    __builtin_amdgcn_sched_barrier(0);
    __builtin_amdgcn_s_barrier();

    for (int t = 0; t < NT; ++t) {
        const int h = t & 1;
        if (t + 1 < NT) {
            const int h1 = h ^ 1;
            const int kg = (t + 1) * 32 + skg;
            #pragma unroll
            for (int s = 0; s < 2; ++s)
                async16(&As[h1][(size_t)(s * 256 + tid) * 8],
                        A + (size_t)(row0 + s * 64 + sr2) * K + kg);
            async16(&Bs[h1][(size_t)tid * 8],
                    B + (size_t)(col0 + sr2) * K + kg);
            asm volatile("s_waitcnt vmcnt(3)" ::: "memory");
        } else {
            asm volatile("s_waitcnt vmcnt(0)" ::: "memory");
        }
        __builtin_amdgcn_sched_barrier(0);
        __builtin_amdgcn_s_barrier();

        const int kq = (lg * 8) ^ fx3;
        bf16x8 af[2], bfr[4];
        #pragma unroll
        for (int mt = 0; mt < 2; ++mt)
            af[mt] = ld_frag(&As[h][(wr + mt * 16 + l15) * 32 + kq]);
        #pragma unroll
        for (int nt = 0; nt < 4; ++nt)
            bfr[nt] = ld_frag(&Bs[h][(nt * 16 + l15) * 32 + kq]);
        #pragma unroll
        for (int mt = 0; mt < 2; ++mt)
            #pragma unroll
            for (int nt = 0; nt < 4; ++nt)
                acc[mt][nt] = __builtin_amdgcn_mfma_f32_16x16x32_bf16(
                    af[mt], bfr[nt], acc[mt][nt], 0, 0, 0);

        __builtin_amdgcn_s_barrier();   // all waves done reading half h
    }

    const int qrow = lg * 4;

    // Fused RoPE: col = col0 + nt*16 + l15, col0 mult of 64 -> d = nt*16+l15.
    // i = d&31 -> (nt&1)*16+l15 ; partner d^32 = acc nt^2 (same thread).
    if (do_rope && col0 < 1024) {
        const float cfreq = 0.28782313662425574f;   // ln(10000)/32
        const float invf0 = __expf(-(float)l15 * cfreq);
        const float invf1 = __expf(-(float)(16 + l15) * cfreq);
        #pragma unroll
        for (int mt = 0; mt < 2; ++mt) {
            #pragma unroll
            for (int r = 0; r < 4; ++r) {
                const int t = (row0 + wr + mt * 16 + qrow + r) & 2047;
                #pragma unroll
                for (int p = 0; p < 2; ++p) {
                    float ang = (float)t * (p ? invf1 : invf0);
                    float s, c;
                    __sincosf(ang, &s, &c);
                    float a = acc[mt][p][r];       // d = p*16+l15 (< 32)
                    float b = acc[mt][p + 2][r];   // d = 32 + p*16+l15
                    acc[mt][p][r]     = a * c - b * s;
                    acc[mt][p + 2][r] = b * c + a * s;
                }
            }
        }
        if (col0 < 512) {   // q: fold softmax scale 1/sqrt(64)
            #pragma unroll
            for (int mt = 0; mt < 2; ++mt)
                #pragma unroll
                for (int nt = 0; nt < 4; ++nt)
                    #pragma unroll
                    for (int r = 0; r < 4; ++r)
                        acc[mt][nt][r] *= 0.125f;
        }
    }

    if (do_rope && col0 >= 1024) {
        // V columns: write transposed into vT[n][h][dim][t] (bf16).
        // Rows rowb..rowb+3 are consecutive t within one n -> one 8B store.
        #pragma unroll
        for (int nt = 0; nt < 4; ++nt) {
            const int local = col0 - 1024 + nt * 16 + l15;
            const int hh = local >> 6;
            const int dd = local & 63;
            #pragma unroll
            for (int mt = 0; mt < 2; ++mt) {
                const int rowb = row0 + wr + mt * 16 + qrow;
                const int nn = rowb >> 11;
                const int tt = rowb & 2047;
                uint2 o;
                o.x = packbf2(acc[mt][nt][0], acc[mt][nt][1]);
                o.y = packbf2(acc[mt][nt][2], acc[mt][nt][3]);
                *(uint2*)(vT + ((size_t)(nn * 8 + hh) * 64 + dd) * 2048 + tt) = o;
            }
        }
        return;
    }

    #pragma unroll
    for (int nt = 0; nt < 4; ++nt) {
        const int col = col0 + nt * 16 + l15;
        const float bv = bias ? bias[col] : 0.f;
        #pragma unroll
        for (int mt = 0; mt < 2; ++mt) {
            const int rowb = row0 + wr + mt * 16 + qrow;
            if (write_bf16) {
                unsigned short* C = (unsigned short*)Cout;
                #pragma unroll
                for (int r = 0; r < 4; ++r)
                    C[(size_t)(rowb + r) * O + col] = f2bf(acc[mt][nt][r] + bv);
            } else {
                float* C = (float*)Cout;
                #pragma unroll
                for (int r = 0; r < 4; ++r)
                    C[(size_t)(rowb + r) * O + col] = acc[mt][nt][r] + bv;
            }
        }
    }
}

// Flash attention with MFMA. Block=256 (4 waves) handles (qt, h, n).
// Staging/barriers: R14-exact (direct global->LDS copies, 3 barriers/tile).
// R17: swapped QK^T — acc_s = mfma(kf, qfrag) computes S^T: row=key
// (nt*16+lg*4+r), col=query (l15). Each thread owns ONE query, 16 scores in
// regs -> softmax is in-register max/sum + 2 shfl_xor(16/32); P written as
// 4x packed ds_write_b64 into Ps[q][k] (same layout pfrag expects). alpha and
// 1/l are redistributed to the PV output layout (query=lg*4+r) via 4 shfl.
// Fully-masked-tile semantics preserved: m stays -1e30 until a valid tile,
// whose alpha=exp(-1e30-m_new)=0 wipes any garbage accumulation (same as the
// pre-swap code). q pre-scaled by 1/8 in the QKV GEMM epilogue.
__global__ __launch_bounds__(256) void attn_mfma_kernel(
    const unsigned short* __restrict__ qkv,
    const unsigned short* __restrict__ vT,
    unsigned short* __restrict__ attnout)
{
    __shared__ __align__(16) unsigned short Kt[64 * 72];      // [key][dim]
    __shared__ __align__(16) unsigned short Vt[64 * 72];      // [dim][key]
    __shared__ __align__(16) unsigned short Ps[4][16 * 72];   // per-wave P[q][k]

    const int qt = blockIdx.x;
    const int h  = blockIdx.y;
    const int n  = blockIdx.z;
    const int t0 = qt * 64;
    const int tid  = threadIdx.x;
    const int wave = tid >> 6;
    const int lane = tid & 63;
    const int l15  = lane & 15;
    const int lg   = lane >> 4;
    const int qrow = lg * 4;

    const size_t base = (size_t)n * 2048 * 1536 + (size_t)h * 64;
    const unsigned short* vTh = vT + (size_t)(n * 8 + h) * 64 * 2048;

    bf16x8 qfrag[2];
    {
        const unsigned short* qp = qkv + base + (size_t)(t0 + wave * 16 + l15) * 1536;
        qfrag[0] = ld_frag(qp + lg * 8);
        qfrag[1] = ld_frag(qp + 32 + lg * 8);
    }

    const int skey = tid >> 2;            // K: key row   | V: dim row
    const int sd0  = (tid & 3) * 16;      // K: dim chunk | V: key chunk

    const int qq = wave * 16 + l15;       // this thread's query (within 64-tile)
    float m_v = -1e30f, l_v = 0.f;
    f32x4 acc_o[4] = {};

    for (int dt = -2; dt <= 2; ++dt) {
        const int kt = qt + dt;
        if (kt < 0 || kt > 31) continue;
        const int s0 = kt * 64;

        {   // stage K (copy) + V (copy of pre-transposed vT)
            const unsigned short* kp = qkv + base + 512 + (size_t)(s0 + skey) * 1536 + sd0;
            *(uint4*)&Kt[skey * 72 + sd0]     = *(const uint4*)kp;
            *(uint4*)&Kt[skey * 72 + sd0 + 8] = *(const uint4*)(kp + 8);

            const unsigned short* vp = vTh + (size_t)skey * 2048 + s0 + sd0;
            *(uint4*)&Vt[skey * 72 + sd0]     = *(const uint4*)vp;
            *(uint4*)&Vt[skey * 72 + sd0 + 8] = *(const uint4*)(vp + 8);
        }
        __syncthreads();

        // ---- S^T = K Q^T (skip fully-masked edge sub-tiles) ----
        f32x4 acc_s[4] = {};
        #pragma unroll
        for (int kstep = 0; kstep < 2; ++kstep) {
            #pragma unroll
            for (int nt = 0; nt < 4; ++nt) {
                if ((dt == -2 && nt < wave) || (dt == 2 && nt > wave)) continue;
                bf16x8 kf = ld_frag(&Kt[(nt * 16 + l15) * 72 + kstep * 32 + lg * 8]);
                acc_s[nt] = __builtin_amdgcn_mfma_f32_16x16x32_bf16(
                    kf, qfrag[kstep], acc_s[nt], 0, 0, 0);
            }
        }

        // ---- per-thread softmax over 16 scores (one query) ----
        float p[4][4];
        float tm = -1e30f;
        #pragma unroll
        for (int nt = 0; nt < 4; ++nt) {
            #pragma unroll
            for (int r = 0; r < 4; ++r) {
                const int diff = dt * 64 + nt * 16 + qrow + r - qq;
                const bool ok = (diff >= -127) && (diff <= 128);
                const float v = ok ? acc_s[nt][r] : -1e30f;   // scale folded in q
                p[nt][r] = v;
                tm = fmaxf(tm, v);
            }
        }
        tm = fmaxf(tm, __shfl_xor(tm, 16, 64));
        tm = fmaxf(tm, __shfl_xor(tm, 32, 64));
        const float m_new = fmaxf(m_v, tm);
        const float alpha = __expf(m_v - m_new);
        float psum = 0.f;
        #pragma unroll
        for (int nt = 0; nt < 4; ++nt) {
            #pragma unroll
            for (int r = 0; r < 4; ++r) {
                const float e = __expf(p[nt][r] - m_new);
                p[nt][r] = e;
                psum += e;
            }
        }
        psum += __shfl_xor(psum, 16, 64);
        psum += __shfl_xor(psum, 32, 64);
        l_v = l_v * alpha + psum;
        m_v = m_new;

        // rescale acc_o: alpha for query lg*4+r lives in lane (lane&48)|(qrow+r)
        #pragma unroll
        for (int r = 0; r < 4; ++r) {
            const float a_r = __shfl(alpha, (lane & 48) + qrow + r, 64);
            #pragma unroll
            for (int nt = 0; nt < 4; ++nt) acc_o[nt][r] *= a_r;
        }

        // P -> Ps[q][k]: k = nt*16 + qrow + {0..3} contiguous -> packed 8B
        #pragma unroll
        for (int nt = 0; nt < 4; ++nt) {
            uint2 o;
            o.x = packbf2(p[nt][0], p[nt][1]);
            o.y = packbf2(p[nt][2], p[nt][3]);
            *(uint2*)&Ps[wave][l15 * 72 + nt * 16 + qrow] = o;
        }

        __syncthreads();

        bf16x8 pfrag[2];
        pfrag[0] = ld_frag(&Ps[wave][l15 * 72 + lg * 8]);
        pfrag[1] = ld_frag(&Ps[wave][l15 * 72 + 32 + lg * 8]);

        #pragma unroll
        for (int kstep = 0; kstep < 2; ++kstep) {
            #pragma unroll
            for (int nt = 0; nt < 4; ++nt) {
                bf16x8 vf = ld_frag(&Vt[(nt * 16 + l15) * 72 + kstep * 32 + lg * 8]);
                acc_o[nt] = __builtin_amdgcn_mfma_f32_16x16x32_bf16(
                    pfrag[kstep], vf, acc_o[nt], 0, 0, 0);
            }
        }
        __syncthreads();
    }

    // 1/l for query lg*4+r lives in lane (lane&48)|(qrow+r)
    const float linv = 1.0f / l_v;
    float inv_l[4];
    #pragma unroll
    for (int r = 0; r < 4; ++r)
        inv_l[r] = __shfl(linv, (lane & 48) + qrow + r, 64);

    #pragma unroll
    for (int r = 0; r < 4; ++r) {
        const int tq = t0 + wave * 16 + qrow + r;
        unsigned short* op = attnout + (size_t)(n * 2048 + tq) * 512 + h * 64;
        #pragma unroll
        for (int nt = 0; nt < 4; ++nt)
            op[nt * 16 + l15] = f2bf(acc_o[nt][r] * inv_l[r]);
    }
}

extern "C" void kernel_launch(void* const* d_in, const int* in_sizes, int n_in,
                              void* d_out, int out_size, void* d_ws, size_t ws_size,
                              hipStream_t stream)
{
    (void)in_sizes; (void)n_in; (void)out_size; (void)ws_size;

    const float* x     = (const float*)d_in[0];
    const float* Wqkv  = (const float*)d_in[1];
    const float* out_w = (const float*)d_in[2];
    const float* out_b = (const float*)d_in[3];
    float* out = (float*)d_out;

    unsigned short* qkvb  = (unsigned short*)d_ws;          // 8192*1536 bf16
    unsigned short* attnb = qkvb + (size_t)8192 * 1536;     // 8192*512  bf16
    unsigned short* xb    = attnb + (size_t)8192 * 512;     // 8192*512  bf16
    unsigned short* wqkvb = xb + (size_t)8192 * 512;        // 1536*512  bf16
    unsigned short* outwb = wqkvb + (size_t)1536 * 512;     // 512*512   bf16
    unsigned short* vTb   = outwb + (size_t)512 * 512;      // 4*8*64*2048 bf16

    // 0) all fp32->bf16 conversions in one launch
    cvt_all<<<5120, 256, 0, stream>>>(x, Wqkv, out_w, xb, wqkvb, outwb);

    // 1) qkv = x @ Wqkv^T with fused RoPE + q-scale (bf16 out; V -> vT)
    gemm_bt_mfma<<<dim3(64, 24), 256, 0, stream>>>(xb, wqkvb, nullptr, qkvb,
                                                   8192, 1536, 512, 1, 1, vTb);
    // 2) flash attention -> attnb bf16
    attn_mfma_kernel<<<dim3(32, 8, 4), 256, 0, stream>>>(qkvb, vTb, attnb);
    // 3) out = attn @ out_w^T + out_b (fp32 out)
    gemm_bt_mfma<<<dim3(64, 8), 256, 0, stream>>>(attnb, outwb, out_b, out,
                                                  8192, 512, 512, 0, 0, nullptr);
}

// Round 6
// 127.242 us; speedup vs baseline: 1.0350x; 1.0350x over previous
//
#include <hip/hip_runtime.h>
#include <math.h>

// ---------------------------------------------------------------------------
// N=4, T=2048, D_MODEL=512, NHEAD=8, HEAD_DIM=64, window -127..+128.
// Pipeline: cvt_all -> bf16 ; qkv = x@Wqkv^T + fused RoPE + q-scale (MFMA,
// LDS-staged BM=128 BN=64 BK=64, XOR-swizzled, global_load_lds) ; flash attn
// (MFMA, swapped-QK^T in-register softmax, 2 barriers/tile) ; out GEMM.
// R19: GEMM reverted to R17-exact (R18's 2-phase BK=32 pipeline regressed:
// doubled barrier count outweighed counted-vmcnt; BN=64/BK=64/5-blocks-CU is
// the local optimum — stop touching its schedule). Attn: removed the mid-tile
// __syncthreads between Ps write and pfrag read — Ps[wave] is wave-private
// and same-wave DS ops are program-ordered (compiler inserts the lgkmcnt
// wait). 3->2 barriers/tile, zero register cost (the isolated, harmless half
// of R16's bundle).
// R17: swapped QK^T in-register softmax (kept, -2.2us).
// R16 lesson: attn reg-prefetch bundle regressed (occupancy) — reverted.
// R15 lesson: occupancy > tile density at K=512 (128x128 GEMM tile reverted).
// R14: V written PRE-TRANSPOSED to vT[n][h][d][t] by the QKV GEMM (kept).
// ---------------------------------------------------------------------------

typedef __attribute__((ext_vector_type(8))) __bf16 bf16x8;
typedef __attribute__((ext_vector_type(4))) float f32x4;

__device__ __forceinline__ unsigned short f2bf(float f) {
    unsigned int u = __float_as_uint(f);
    u += 0x7fffu + ((u >> 16) & 1u);
    return (unsigned short)(u >> 16);
}
__device__ __forceinline__ unsigned int packbf2(float a, float b) {
    unsigned int ua = __float_as_uint(a); ua += 0x7fffu + ((ua >> 16) & 1u);
    unsigned int ub = __float_as_uint(b); ub += 0x7fffu + ((ub >> 16) & 1u);
    return (ua >> 16) | (ub & 0xffff0000u);
}
__device__ __forceinline__ bf16x8 as_bf16x8(uint4 u) {
    union { uint4 u4; bf16x8 v; } c; c.u4 = u; return c.v;
}
__device__ __forceinline__ bf16x8 ld_frag(const unsigned short* p) {
    return as_bf16x8(*(const uint4*)p);
}

__device__ __forceinline__ void async16(void* lds, const void* g) {
    __builtin_amdgcn_global_load_lds(
        (const __attribute__((address_space(1))) void*)g,
        (__attribute__((address_space(3))) void*)lds,
        16, 0, 0);
}

// One kernel converts all three fp32 inputs to bf16 (4 elems/thread).
__global__ __launch_bounds__(256) void cvt_all(
    const float* __restrict__ x, const float* __restrict__ w1,
    const float* __restrict__ w2,
    unsigned short* __restrict__ xb, unsigned short* __restrict__ w1b,
    unsigned short* __restrict__ w2b)
{
    const int n_x  = 8192 * 512 / 4;
    const int n_w1 = 1536 * 512 / 4;
    const int n_w2 = 512 * 512 / 4;
    int i = blockIdx.x * 256 + threadIdx.x;
    const float* in; unsigned short* out; int j;
    if (i < n_x)                    { in = x;  out = xb;  j = i; }
    else if (i < n_x + n_w1)        { in = w1; out = w1b; j = i - n_x; }
    else if (i < n_x + n_w1 + n_w2) { in = w2; out = w2b; j = i - n_x - n_w1; }
    else return;
    float4 v = *(const float4*)(in + 4 * (size_t)j);
    uint2 o;
    o.x = packbf2(v.x, v.y);
    o.y = packbf2(v.z, v.w);
    *(uint2*)(out + 4 * (size_t)j) = o;
}

// C[M,O] = A[M,K](bf16) * B[O,K](bf16)^T (+bias). Output fp32 or bf16.
// BM=128, BN=64, BK=64. Block=256 (4 waves); wave w computes rows
// [w*32,+32) x all 64 cols (mt=2, nt=4; acc 32 AGPR).
// __launch_bounds__(256,5): target 5 blocks/CU (~102-reg cap) so barrier
// drains overlap across resident blocks. (R15/R18 lessons: occupancy beats
// density AND beats counted-vmcnt pipelining at K=512 — schedule frozen.)
// Grid: blockIdx.x = ROW block (fastest; R11 showed col-fastest regresses).
// LDS XOR-swizzled k-offset: staging dests stay chunk-contiguous
// (global_load_lds constraint), frag reads conflict-free.
// do_rope: qkv layout (O=1536); RoPE cols<1024 (partner col^32 == acc nt^2,
// same thread), fold 1/8 into q cols<512. V cols (>=1024) are written
// transposed to vT[n][h][dim][t] as packed 8B stores (attn consumes V^T).
__global__ __launch_bounds__(256, 5) void gemm_bt_mfma(
    const unsigned short* __restrict__ A, const unsigned short* __restrict__ B,
    const float* __restrict__ bias, void* __restrict__ Cout,
    int M, int O, int K, int write_bf16, int do_rope,
    unsigned short* __restrict__ vT)
{
    __shared__ __align__(16) unsigned short As[128 * 64];   // 16 KB
    __shared__ __align__(16) unsigned short Bs[64 * 64];    // 8 KB

    const int tid  = threadIdx.x;
    const int wave = tid >> 6;
    const int lane = tid & 63;
    const int l15  = lane & 15;
    const int lg   = lane >> 4;
    const int row0 = blockIdx.x * 128;
    const int col0 = blockIdx.y * 64;
    const int wr   = wave * 32;

    f32x4 acc[2][4] = {};

    const int srow = tid >> 3;
    const int skg  = ((tid & 7) * 8) ^ ((srow & 7) * 8);
    const int fx   = (l15 & 7) * 8;

    for (int k0 = 0; k0 < K; k0 += 64) {
        #pragma unroll
        for (int s = 0; s < 4; ++s)
            async16(&As[(size_t)(s * 256 + tid) * 8],
                    A + (size_t)(row0 + s * 32 + srow) * K + k0 + skg);
        #pragma unroll
        for (int s = 0; s < 2; ++s)
            async16(&Bs[(size_t)(s * 256 + tid) * 8],
                    B + (size_t)(col0 + s * 32 + srow) * K + k0 + skg);
        __syncthreads();

        #pragma unroll
        for (int kstep = 0; kstep < 2; ++kstep) {
            const int kq = (kstep * 32 + lg * 8) ^ fx;
            bf16x8 af[2], bfr[4];
            #pragma unroll
            for (int mt = 0; mt < 2; ++mt)
                af[mt] = ld_frag(&As[(wr + mt * 16 + l15) * 64 + kq]);
            #pragma unroll
            for (int nt = 0; nt < 4; ++nt)
                bfr[nt] = ld_frag(&Bs[(nt * 16 + l15) * 64 + kq]);
            #pragma unroll
            for (int mt = 0; mt < 2; ++mt)
                #pragma unroll
                for (int nt = 0; nt < 4; ++nt)
                    acc[mt][nt] = __builtin_amdgcn_mfma_f32_16x16x32_bf16(
                        af[mt], bfr[nt], acc[mt][nt], 0, 0, 0);
        }
        __syncthreads();
    }

    const int qrow = lg * 4;

    // Fused RoPE: col = col0 + nt*16 + l15, col0 mult of 64 -> d = nt*16+l15.
    // i = d&31 -> (nt&1)*16+l15 ; partner d^32 = acc nt^2 (same thread).
    if (do_rope && col0 < 1024) {
        const float cfreq = 0.28782313662425574f;   // ln(10000)/32
        const float invf0 = __expf(-(float)l15 * cfreq);
        const float invf1 = __expf(-(float)(16 + l15) * cfreq);
        #pragma unroll
        for (int mt = 0; mt < 2; ++mt) {
            #pragma unroll
            for (int r = 0; r < 4; ++r) {
                const int t = (row0 + wr + mt * 16 + qrow + r) & 2047;
                #pragma unroll
                for (int p = 0; p < 2; ++p) {
                    float ang = (float)t * (p ? invf1 : invf0);
                    float s, c;
                    __sincosf(ang, &s, &c);
                    float a = acc[mt][p][r];       // d = p*16+l15 (< 32)
                    float b = acc[mt][p + 2][r];   // d = 32 + p*16+l15
                    acc[mt][p][r]     = a * c - b * s;
                    acc[mt][p + 2][r] = b * c + a * s;
                }
            }
        }
        if (col0 < 512) {   // q: fold softmax scale 1/sqrt(64)
            #pragma unroll
            for (int mt = 0; mt < 2; ++mt)
                #pragma unroll
                for (int nt = 0; nt < 4; ++nt)
                    #pragma unroll
                    for (int r = 0; r < 4; ++r)
                        acc[mt][nt][r] *= 0.125f;
        }
    }

    if (do_rope && col0 >= 1024) {
        // V columns: write transposed into vT[n][h][dim][t] (bf16).
        // Rows rowb..rowb+3 are consecutive t within one n -> one 8B store.
        #pragma unroll
        for (int nt = 0; nt < 4; ++nt) {
            const int local = col0 - 1024 + nt * 16 + l15;
            const int hh = local >> 6;
            const int dd = local & 63;
            #pragma unroll
            for (int mt = 0; mt < 2; ++mt) {
                const int rowb = row0 + wr + mt * 16 + qrow;
                const int nn = rowb >> 11;
                const int tt = rowb & 2047;
                uint2 o;
                o.x = packbf2(acc[mt][nt][0], acc[mt][nt][1]);
                o.y = packbf2(acc[mt][nt][2], acc[mt][nt][3]);
                *(uint2*)(vT + ((size_t)(nn * 8 + hh) * 64 + dd) * 2048 + tt) = o;
            }
        }
        return;
    }

    #pragma unroll
    for (int nt = 0; nt < 4; ++nt) {
        const int col = col0 + nt * 16 + l15;
        const float bv = bias ? bias[col] : 0.f;
        #pragma unroll
        for (int mt = 0; mt < 2; ++mt) {
            const int rowb = row0 + wr + mt * 16 + qrow;
            if (write_bf16) {
                unsigned short* C = (unsigned short*)Cout;
                #pragma unroll
                for (int r = 0; r < 4; ++r)
                    C[(size_t)(rowb + r) * O + col] = f2bf(acc[mt][nt][r] + bv);
            } else {
                float* C = (float*)Cout;
                #pragma unroll
                for (int r = 0; r < 4; ++r)
                    C[(size_t)(rowb + r) * O + col] = acc[mt][nt][r] + bv;
            }
        }
    }
}

// Flash attention with MFMA. Block=256 (4 waves) handles (qt, h, n).
// Staging: R14-exact (direct global->LDS copies). R19: 2 barriers/tile —
// the barrier between Ps write and pfrag read is removed (Ps[wave] is
// wave-private; same-wave DS ops are program-ordered, compiler inserts the
// lgkmcnt wait for the same-array dependency).
// R17: swapped QK^T — acc_s = mfma(kf, qfrag) computes S^T: row=key
// (nt*16+lg*4+r), col=query (l15). Each thread owns ONE query, 16 scores in
// regs -> softmax is in-register max/sum + 2 shfl_xor(16/32); P written as
// 4x packed ds_write_b64 into Ps[q][k] (same layout pfrag expects). alpha and
// 1/l are redistributed to the PV output layout (query=lg*4+r) via 4 shfl.
// Fully-masked-tile semantics preserved: m stays -1e30 until a valid tile,
// whose alpha=exp(-1e30-m_new)=0 wipes any garbage accumulation.
// q pre-scaled by 1/8 in the QKV GEMM epilogue.
__global__ __launch_bounds__(256) void attn_mfma_kernel(
    const unsigned short* __restrict__ qkv,
    const unsigned short* __restrict__ vT,
    unsigned short* __restrict__ attnout)
{
    __shared__ __align__(16) unsigned short Kt[64 * 72];      // [key][dim]
    __shared__ __align__(16) unsigned short Vt[64 * 72];      // [dim][key]
    __shared__ __align__(16) unsigned short Ps[4][16 * 72];   // per-wave P[q][k]

    const int qt = blockIdx.x;
    const int h  = blockIdx.y;
    const int n  = blockIdx.z;
    const int t0 = qt * 64;
    const int tid  = threadIdx.x;
    const int wave = tid >> 6;
    const int lane = tid & 63;
    const int l15  = lane & 15;
    const int lg   = lane >> 4;
    const int qrow = lg * 4;

    const size_t base = (size_t)n * 2048 * 1536 + (size_t)h * 64;
    const unsigned short* vTh = vT + (size_t)(n * 8 + h) * 64 * 2048;

    bf16x8 qfrag[2];
    {
        const unsigned short* qp = qkv + base + (size_t)(t0 + wave * 16 + l15) * 1536;
        qfrag[0] = ld_frag(qp + lg * 8);
        qfrag[1] = ld_frag(qp + 32 + lg * 8);
    }

    const int skey = tid >> 2;            // K: key row   | V: dim row
    const int sd0  = (tid & 3) * 16;      // K: dim chunk | V: key chunk

    const int qq = wave * 16 + l15;       // this thread's query (within 64-tile)
    float m_v = -1e30f, l_v = 0.f;
    f32x4 acc_o[4] = {};

    for (int dt = -2; dt <= 2; ++dt) {
        const int kt = qt + dt;
        if (kt < 0 || kt > 31) continue;
        const int s0 = kt * 64;

        {   // stage K (copy) + V (copy of pre-transposed vT)
            const unsigned short* kp = qkv + base + 512 + (size_t)(s0 + skey) * 1536 + sd0;
            *(uint4*)&Kt[skey * 72 + sd0]     = *(const uint4*)kp;
            *(uint4*)&Kt[skey * 72 + sd0 + 8] = *(const uint4*)(kp + 8);

            const unsigned short* vp = vTh + (size_t)skey * 2048 + s0 + sd0;
            *(uint4*)&Vt[skey * 72 + sd0]     = *(const uint4*)vp;
            *(uint4*)&Vt[skey * 72 + sd0 + 8] = *(const uint4*)(vp + 8);
        }
        __syncthreads();

        // ---- S^T = K Q^T (skip fully-masked edge sub-tiles) ----
        f32x4 acc_s[4] = {};
        #pragma unroll
        for (int kstep = 0; kstep < 2; ++kstep) {
            #pragma unroll
            for (int nt = 0; nt < 4; ++nt) {
                if ((dt == -2 && nt < wave) || (dt == 2 && nt > wave)) continue;
                bf16x8 kf = ld_frag(&Kt[(nt * 16 + l15) * 72 + kstep * 32 + lg * 8]);
                acc_s[nt] = __builtin_amdgcn_mfma_f32_16x16x32_bf16(
                    kf, qfrag[kstep], acc_s[nt], 0, 0, 0);
            }
        }

        // ---- per-thread softmax over 16 scores (one query) ----
        float p[4][4];
        float tm = -1e30f;
        #pragma unroll
        for (int nt = 0; nt < 4; ++nt) {
            #pragma unroll
            for (int r = 0; r < 4; ++r) {
                const int diff = dt * 64 + nt * 16 + qrow + r - qq;
                const bool ok = (diff >= -127) && (diff <= 128);
                const float v = ok ? acc_s[nt][r] : -1e30f;   // scale folded in q
                p[nt][r] = v;
                tm = fmaxf(tm, v);
            }
        }
        tm = fmaxf(tm, __shfl_xor(tm, 16, 64));
        tm = fmaxf(tm, __shfl_xor(tm, 32, 64));
        const float m_new = fmaxf(m_v, tm);
        const float alpha = __expf(m_v - m_new);
        float psum = 0.f;
        #pragma unroll
        for (int nt = 0; nt < 4; ++nt) {
            #pragma unroll
            for (int r = 0; r < 4; ++r) {
                const float e = __expf(p[nt][r] - m_new);
                p[nt][r] = e;
                psum += e;
            }
        }
        psum += __shfl_xor(psum, 16, 64);
        psum += __shfl_xor(psum, 32, 64);
        l_v = l_v * alpha + psum;
        m_v = m_new;

        // rescale acc_o: alpha for query lg*4+r lives in lane (lane&48)|(qrow+r)
        #pragma unroll
        for (int r = 0; r < 4; ++r) {
            const float a_r = __shfl(alpha, (lane & 48) + qrow + r, 64);
            #pragma unroll
            for (int nt = 0; nt < 4; ++nt) acc_o[nt][r] *= a_r;
        }

        // P -> Ps[q][k]: k = nt*16 + qrow + {0..3} contiguous -> packed 8B.
        // Wave-private: no barrier before the pfrag read (same-wave DS order).
        #pragma unroll
        for (int nt = 0; nt < 4; ++nt) {
            uint2 o;
            o.x = packbf2(p[nt][0], p[nt][1]);
            o.y = packbf2(p[nt][2], p[nt][3]);
            *(uint2*)&Ps[wave][l15 * 72 + nt * 16 + qrow] = o;
        }

        bf16x8 pfrag[2];
        pfrag[0] = ld_frag(&Ps[wave][l15 * 72 + lg * 8]);
        pfrag[1] = ld_frag(&Ps[wave][l15 * 72 + 32 + lg * 8]);

        #pragma unroll
        for (int kstep = 0; kstep < 2; ++kstep) {
            #pragma unroll
            for (int nt = 0; nt < 4; ++nt) {
                bf16x8 vf = ld_frag(&Vt[(nt * 16 + l15) * 72 + kstep * 32 + lg * 8]);
                acc_o[nt] = __builtin_amdgcn_mfma_f32_16x16x32_bf16(
                    pfrag[kstep], vf, acc_o[nt], 0, 0, 0);
            }
        }
        __syncthreads();   // all waves done reading Kt/Vt before next stage
    }

    // 1/l for query lg*4+r lives in lane (lane&48)|(qrow+r)
    const float linv = 1.0f / l_v;
    float inv_l[4];
    #pragma unroll
    for (int r = 0; r < 4; ++r)
        inv_l[r] = __shfl(linv, (lane & 48) + qrow + r, 64);

    #pragma unroll
    for (int r = 0; r < 4; ++r) {
        const int tq = t0 + wave * 16 + qrow + r;
        unsigned short* op = attnout + (size_t)(n * 2048 + tq) * 512 + h * 64;
        #pragma unroll
        for (int nt = 0; nt < 4; ++nt)
            op[nt * 16 + l15] = f2bf(acc_o[nt][r] * inv_l[r]);
    }
}

extern "C" void kernel_launch(void* const* d_in, const int* in_sizes, int n_in,
                              void* d_out, int out_size, void* d_ws, size_t ws_size,
                              hipStream_t stream)
{
    (void)in_sizes; (void)n_in; (void)out_size; (void)ws_size;

    const float* x     = (const float*)d_in[0];
    const float* Wqkv  = (const float*)d_in[1];
    const float* out_w = (const float*)d_in[2];
    const float* out_b = (const float*)d_in[3];
    float* out = (float*)d_out;

    unsigned short* qkvb  = (unsigned short*)d_ws;          // 8192*1536 bf16
    unsigned short* attnb = qkvb + (size_t)8192 * 1536;     // 8192*512  bf16
    unsigned short* xb    = attnb + (size_t)8192 * 512;     // 8192*512  bf16
    unsigned short* wqkvb = xb + (size_t)8192 * 512;        // 1536*512  bf16
    unsigned short* outwb = wqkvb + (size_t)1536 * 512;     // 512*512   bf16
    unsigned short* vTb   = outwb + (size_t)512 * 512;      // 4*8*64*2048 bf16

    // 0) all fp32->bf16 conversions in one launch
    cvt_all<<<5120, 256, 0, stream>>>(x, Wqkv, out_w, xb, wqkvb, outwb);

    // 1) qkv = x @ Wqkv^T with fused RoPE + q-scale (bf16 out; V -> vT)
    gemm_bt_mfma<<<dim3(64, 24), 256, 0, stream>>>(xb, wqkvb, nullptr, qkvb,
                                                   8192, 1536, 512, 1, 1, vTb);
    // 2) flash attention -> attnb bf16
    attn_mfma_kernel<<<dim3(32, 8, 4), 256, 0, stream>>>(qkvb, vTb, attnb);
    // 3) out = attn @ out_w^T + out_b (fp32 out)
    gemm_bt_mfma<<<dim3(64, 8), 256, 0, stream>>>(attnb, outwb, out_b, out,
                                                  8192, 512, 512, 0, 0, nullptr);
}